// Round 1
// 147.786 us; speedup vs baseline: 1.1105x; 1.1105x over previous
//
#include <hip/hip_runtime.h>
#include <math.h>

#define B 4
#define N 256
#define DIN 4
#define D 64
#define NH 4
#define NL 2
#define DH 16

constexpr float EPS = 1e-5f;
constexpr float SLOPE = 0.01f;

// ---------------------------------------------------------------------------
// Direct global->LDS DMA staging: each call moves 64 lanes x 16B per wave.
// LDS dest is wave-uniform base + lane*16 (hardware constraint), source is
// the matching linear global address. Drained by the next __syncthreads().
// NF4 = number of float4s to copy (multiple of 512 for a 512-thread block).
// ---------------------------------------------------------------------------
template <int NF4>
__device__ __forceinline__ void stage(float* dst, const float* src, int t) {
    int lane = t & 63, w = t >> 6;
#pragma unroll
    for (int i0 = 0; i0 < NF4; i0 += 512) {
        int base = i0 + w * 64;
        __builtin_amdgcn_global_load_lds(
            (const __attribute__((address_space(1))) void*)(src + 4 * (base + lane)),
            (__attribute__((address_space(3))) void*)(dst + 4 * base),
            16, 0, 0);
    }
}

// ---------------------------------------------------------------------------
// P1: rowsum. grid 256, block 256. Wave w -> row bi = cb*4+w; lane owns 4 j's.
// Block 0 also zero-inits the BN stat accumulators (consumed two kernels later).
// ---------------------------------------------------------------------------
__global__ void __launch_bounds__(256) k_rowsum(
    const float* __restrict__ feature, const float* __restrict__ W1,
    const float* __restrict__ b1, const float* __restrict__ mw,
    const float* __restrict__ mb, float* __restrict__ rs,
    float* __restrict__ bnacc /* [128]: macc|sacc */) {
    __shared__ float M[16];
    __shared__ float C[4];
    int t = threadIdx.x;
    int lane = t & 63, w = t >> 6;
    int cb = blockIdx.x;
    if (cb == 0 && t < 128) bnacc[t] = 0.f;
    if (t < 16) {
        int n = t >> 2, kk = t & 3;
        float s = 0.f;
        for (int d = 0; d < D; ++d) s += W1[kk * D + d] * mw[n * D + d];
        M[t] = s;
    } else if (t < 20) {
        int n = t - 16;
        float s = mb[n];
        for (int d = 0; d < D; ++d) s += b1[d] * mw[n * D + d];
        C[n] = s;
    }
    __syncthreads();

    int bi = cb * 4 + w;
    const float4* fb = (const float4*)(feature) + (size_t)bi * N;
    float sn[4] = {0.f, 0.f, 0.f, 0.f};
#pragma unroll
    for (int m = 0; m < 4; ++m) {
        float4 f = fb[lane + 64 * m];
#pragma unroll
        for (int n = 0; n < 4; ++n) {
            float s = C[n] + f.x * M[n*4+0] + f.y * M[n*4+1] + f.z * M[n*4+2] + f.w * M[n*4+3];
            s = (s >= 0.f) ? s : SLOPE * s;
            sn[n] += __expf(s);
        }
    }
#pragma unroll
    for (int n = 0; n < 4; ++n)
#pragma unroll
        for (int off = 32; off > 0; off >>= 1) sn[n] += __shfl_xor(sn[n], off);
    if (lane == 0) {
        float4 o = {sn[0], sn[1], sn[2], sn[3]};
        *(float4*)(rs + (size_t)bi * 4) = o;
    }
}

// ---------------------------------------------------------------------------
// P2: aggregate + h projection + BN partial sums (atomic).
// grid 256 (b = cb>>6, j0 = (cb&63)*4), block 256 (thread = i, 64B contiguous).
// ---------------------------------------------------------------------------
__global__ void __launch_bounds__(256) k_aggregate(
    const float* __restrict__ feature, const float* __restrict__ W1,
    const float* __restrict__ b1, const float* __restrict__ mw,
    const float* __restrict__ mb, const float* __restrict__ rs,
    float* __restrict__ h, float* __restrict__ bnacc) {
    __shared__ float M[16];
    __shared__ float C[4];
    __shared__ float part[80];   // [4 waves][20]
    __shared__ float gacc[20];   // [4][5]
    __shared__ float hs[4][D];
    int t = threadIdx.x;
    int lane = t & 63, w = t >> 6;
    int cb = blockIdx.x;
    if (t < 16) {
        int n = t >> 2, kk = t & 3;
        float s = 0.f;
        for (int d = 0; d < D; ++d) s += W1[kk * D + d] * mw[n * D + d];
        M[t] = s;
    } else if (t < 20) {
        int n = t - 16;
        float s = mb[n];
        for (int d = 0; d < D; ++d) s += b1[d] * mw[n * D + d];
        C[n] = s;
    }
    __syncthreads();

    int b = cb >> 6, j0 = (cb & 63) * 4;
    int i = t;
    const float4* fb = (const float4*)(feature) + ((size_t)(b * N + i) * N + j0);
    float4 f[4];
#pragma unroll
    for (int jj = 0; jj < 4; ++jj) f[jj] = fb[jj];
    float4 r4 = *(const float4*)(rs + (size_t)(b * N + i) * 4);
    float rinv[4] = {1.f / r4.x, 1.f / r4.y, 1.f / r4.z, 1.f / r4.w};
    float acc[4][5];
#pragma unroll
    for (int jj = 0; jj < 4; ++jj) {
        float wbar = 0.f;
#pragma unroll
        for (int n = 0; n < 4; ++n) {
            float s = C[n] + f[jj].x * M[n*4+0] + f[jj].y * M[n*4+1] + f[jj].z * M[n*4+2] + f[jj].w * M[n*4+3];
            s = (s >= 0.f) ? s : SLOPE * s;
            wbar += __expf(s) * rinv[n];
        }
        wbar *= 0.25f;
        acc[jj][0] = wbar * f[jj].x; acc[jj][1] = wbar * f[jj].y;
        acc[jj][2] = wbar * f[jj].z; acc[jj][3] = wbar * f[jj].w;
        acc[jj][4] = wbar;
    }
#pragma unroll
    for (int jj = 0; jj < 4; ++jj)
#pragma unroll
        for (int c = 0; c < 5; ++c)
#pragma unroll
            for (int off = 32; off > 0; off >>= 1) acc[jj][c] += __shfl_xor(acc[jj][c], off);
    if (lane == 0) {
#pragma unroll
        for (int jj = 0; jj < 4; ++jj)
#pragma unroll
            for (int c = 0; c < 5; ++c) part[w * 20 + jj * 5 + c] = acc[jj][c];
    }
    __syncthreads();
    if (t < 20) gacc[t] = part[t] + part[20 + t] + part[40 + t] + part[60 + t];
    __syncthreads();
    // h write: wave w = token j0+w, lane = channel
    float hv = gacc[w * 5 + 4] * b1[lane];
#pragma unroll
    for (int kk = 0; kk < 4; ++kk) hv += gacc[w * 5 + kk] * W1[kk * D + lane];
    h[((size_t)(b * N + j0 + w)) * D + lane] = hv;
    hs[w][lane] = hv;
    __syncthreads();
    if (w == 0) {
        float s = hs[0][lane] + hs[1][lane] + hs[2][lane] + hs[3][lane];
        float sq = hs[0][lane]*hs[0][lane] + hs[1][lane]*hs[1][lane]
                 + hs[2][lane]*hs[2][lane] + hs[3][lane]*hs[3][lane];
        atomicAdd(bnacc + lane, s);
        atomicAdd(bnacc + D + lane, sq);
    }
}

// ---------------------------------------------------------------------------
// P3: BN finalize + apply + QKV for layer 0.
// grid 256, block 512 (8 waves): wave = (token tok4, k-half kh). Weights are
// DMA-staged to LDS first; each wave reduces 32 of the 64 kk's; partials are
// combined through LDS. 2 waves/SIMD + LDS-resident weights hide latency.
// ---------------------------------------------------------------------------
__global__ void __launch_bounds__(512, 2) k_qkv0(
    const float* __restrict__ h, const float* __restrict__ bnacc,
    const float* __restrict__ bn_g, const float* __restrict__ bn_b,
    const float* __restrict__ Wq, const float* __restrict__ bq,
    const float* __restrict__ Wk, const float* __restrict__ bk,
    const float* __restrict__ Wv, const float* __restrict__ bv,
    float* __restrict__ x, float* __restrict__ q,
    float* __restrict__ k, float* __restrict__ v) {
    __shared__ __align__(16) float xsh[4 * D];
    __shared__ __align__(16) float pp[8 * 192];
    __shared__ __align__(16) float WqL[D * D];
    __shared__ __align__(16) float WkL[D * D];
    __shared__ __align__(16) float WvL[D * D];
    int t = threadIdx.x;
    int lane = t & 63, w = t >> 6;
    int tok4 = w & 3, kh = w >> 2;
    int token = blockIdx.x * 4 + tok4;
    int b = token >> 8, n = token & (N - 1);
    int ch = lane;

    // async weight staging (drained by the first __syncthreads)
    stage<D * D / 4>(WqL, Wq, t);
    stage<D * D / 4>(WkL, Wk, t);
    stage<D * D / 4>(WvL, Wv, t);

    float mean = bnacc[ch] * (1.0f / (B * N));
    float var = bnacc[D + ch] * (1.0f / (B * N)) - mean * mean;
    float inv = rsqrtf(var + EPS);
    size_t xi = (size_t)token * D + ch;
    float xv = bn_g[ch] * (h[xi] - mean) * inv + bn_b[ch];
    float bq_r = bq[ch], bk_r = bk[ch], bv_r = bv[ch];
    if (kh == 0) {
        x[xi] = xv;
        xsh[tok4 * D + ch] = xv;
    }
    __syncthreads();

    const float4* xr4 = (const float4*)(xsh + tok4 * D + kh * 32);
    float aq0=0.f, aq1=0.f, ak0=0.f, ak1=0.f, av0=0.f, av1=0.f;
#pragma unroll
    for (int k4 = 0; k4 < 8; ++k4) {
        float4 xx = xr4[k4];
        int kk = kh * 32 + k4 * 4;
        aq0 += xx.x * WqL[(kk+0)*D+ch] + xx.z * WqL[(kk+2)*D+ch];
        aq1 += xx.y * WqL[(kk+1)*D+ch] + xx.w * WqL[(kk+3)*D+ch];
        ak0 += xx.x * WkL[(kk+0)*D+ch] + xx.z * WkL[(kk+2)*D+ch];
        ak1 += xx.y * WkL[(kk+1)*D+ch] + xx.w * WkL[(kk+3)*D+ch];
        av0 += xx.x * WvL[(kk+0)*D+ch] + xx.z * WvL[(kk+2)*D+ch];
        av1 += xx.y * WvL[(kk+1)*D+ch] + xx.w * WvL[(kk+3)*D+ch];
    }
    float* ppw = pp + w * 192;
    ppw[ch] = aq0 + aq1;
    ppw[64 + ch] = ak0 + ak1;
    ppw[128 + ch] = av0 + av1;
    __syncthreads();
    if (kh == 0) {
        int head = ch >> 4, dh = ch & (DH - 1);
        size_t oidx = (((size_t)(b * NH + head)) * N + n) * DH + dh;
        q[oidx] = bq_r + pp[tok4*192 + ch] + pp[(tok4+4)*192 + ch];
        k[oidx] = bk_r + pp[tok4*192 + 64 + ch] + pp[(tok4+4)*192 + 64 + ch];
        v[oidx] = bv_r + pp[tok4*192 + 128 + ch] + pp[(tok4+4)*192 + 128 + ch];
    }
}

// ---------------------------------------------------------------------------
// Fused layer tail: attention + O-proj + LN1 + FFN + LN2 (+ next-layer QKV).
// grid (B, N/4), block 512 (8 waves, 2/SIMD).
//  - All weights DMA-staged to LDS at entry (141 KB, 1 block/CU) so the
//    matmul phases never touch global memory.
//  - Attention: wave = (head w&3, query-pair w>>2), lanes own keys.
//  - Post phases: wave = (token w&3, k-half w>>2) split-K; partials combined
//    through pp[] in LDS. Both k-half waves redundantly compute LN stats
//    (bitwise identical) so no extra broadcast is needed.
// ---------------------------------------------------------------------------
__global__ void __launch_bounds__(512, 2) k_layer(
    const float* __restrict__ q, const float* __restrict__ k,
    const float* __restrict__ v,
    const float* __restrict__ Wo, const float* __restrict__ bo,
    const float* __restrict__ ln1g, const float* __restrict__ ln1b,
    const float* __restrict__ Wff1, const float* __restrict__ bff1,
    const float* __restrict__ Wff2, const float* __restrict__ bff2,
    const float* __restrict__ ln2g, const float* __restrict__ ln2b,
    const float* __restrict__ Wqn, const float* __restrict__ bqn,
    const float* __restrict__ Wkn, const float* __restrict__ bkn,
    const float* __restrict__ Wvn, const float* __restrict__ bvn,
    float* __restrict__ qo, float* __restrict__ ko, float* __restrict__ vo,
    float* __restrict__ x) {
    __shared__ __align__(16) float attS[4 * D];     // att output / x-new tile
    __shared__ __align__(16) float xs1[4 * D];
    __shared__ __align__(16) float f1s[4 * 2 * D];
    __shared__ __align__(16) float pp[8 * 192];     // split-K partials
    __shared__ __align__(16) float WoL[D * D];
    __shared__ __align__(16) float Wff1L[D * 2 * D];
    __shared__ __align__(16) float Wff2L[2 * D * D];
    __shared__ __align__(16) float WqnL[D * D];
    __shared__ __align__(16) float WknL[D * D];
    __shared__ __align__(16) float WvnL[D * D];

    int t = threadIdx.x;
    int lane = t & 63, w = t >> 6;
    int b = blockIdx.x;
    int q0 = blockIdx.y * 4;
    int h_ = w & 3, qpair = w >> 2;
    int tok4 = w & 3, kh = w >> 2;
    int token = q0 + tok4;
    int ch = lane;

    // ---- K/V register loads issued first ----
    int bh = b * NH + h_;
    const float* kb = k + (size_t)bh * N * DH;
    const float* vb = v + (size_t)bh * N * DH;
    float4 Kr[4][4], Vr[4][4];
#pragma unroll
    for (int j = 0; j < 4; ++j) {
        int key = lane + 64 * j;
#pragma unroll
        for (int c = 0; c < 4; ++c) {
            Kr[j][c] = *(const float4*)(kb + (size_t)key * DH + 4 * c);
            Vr[j][c] = *(const float4*)(vb + (size_t)key * DH + 4 * c);
        }
    }

    // ---- early per-lane param loads (consumed after the barrier) ----
    size_t xidx = ((size_t)b * N + token) * D + ch;
    float xv = x[xidx];
    float bo_r = bo[ch], l1g = ln1g[ch], l1b = ln1b[ch];
    float bf1_r = bff1[kh * D + ch];
    float bf2_r = bff2[ch], l2g = ln2g[ch], l2b = ln2b[ch];
    float bq_r = 0.f, bk_r = 0.f, bv_r = 0.f;
    if (Wqn != nullptr) { bq_r = bqn[ch]; bk_r = bkn[ch]; bv_r = bvn[ch]; }

    // ---- async weight staging; overlaps the attention phase ----
    stage<1024>(WoL, Wo, t);
    stage<2048>(Wff1L, Wff1, t);
    stage<2048>(Wff2L, Wff2, t);
    if (Wqn != nullptr) {
        stage<1024>(WqnL, Wqn, t);
        stage<1024>(WknL, Wkn, t);
        stage<1024>(WvnL, Wvn, t);
    }

    // ---- attention: 2 queries per wave ----
#pragma unroll
    for (int qq2 = 0; qq2 < 2; ++qq2) {
        int qq = qpair * 2 + qq2;
        const float* qp = q + ((size_t)bh * N + q0 + qq) * DH;  // wave-uniform
        float sq[DH];
#pragma unroll
        for (int d = 0; d < DH; ++d) sq[d] = qp[d];
        float s[4];
#pragma unroll
        for (int j = 0; j < 4; ++j) {
            float a = 0.f;
#pragma unroll
            for (int c = 0; c < 4; ++c)
                a += sq[4*c+0]*Kr[j][c].x + sq[4*c+1]*Kr[j][c].y +
                     sq[4*c+2]*Kr[j][c].z + sq[4*c+3]*Kr[j][c].w;
            s[j] = a;
        }
        float m = fmaxf(fmaxf(s[0], s[1]), fmaxf(s[2], s[3]));
#pragma unroll
        for (int off = 32; off > 0; off >>= 1) m = fmaxf(m, __shfl_xor(m, off));
        float p[4], lsum = 0.f;
#pragma unroll
        for (int j = 0; j < 4; ++j) { p[j] = __expf((s[j] - m) * 0.25f); lsum += p[j]; }
#pragma unroll
        for (int off = 32; off > 0; off >>= 1) lsum += __shfl_xor(lsum, off);
        float o[DH];
#pragma unroll
        for (int d = 0; d < DH; ++d) o[d] = 0.f;
#pragma unroll
        for (int j = 0; j < 4; ++j) {
#pragma unroll
            for (int c = 0; c < 4; ++c) {
                o[4*c+0] += p[j] * Vr[j][c].x;
                o[4*c+1] += p[j] * Vr[j][c].y;
                o[4*c+2] += p[j] * Vr[j][c].z;
                o[4*c+3] += p[j] * Vr[j][c].w;
            }
        }
#pragma unroll
        for (int d = 0; d < DH; ++d) {
#pragma unroll
            for (int off = 32; off > 0; off >>= 1) o[d] += __shfl_xor(o[d], off);
        }
        if (lane == 0) {
            float rl = 1.f / lsum;
#pragma unroll
            for (int d = 0; d < DH; ++d) attS[qq * D + h_ * DH + d] = o[d] * rl;
        }
    }
    __syncthreads();   // attS ready + all staged weights landed

    // ---- O-proj (split-K) ----
    float* ppw = pp + w * 192;
    {
        const float4* ar4 = (const float4*)(attS + tok4 * D + kh * 32);
        float a0=0.f, a1=0.f, a2=0.f, a3=0.f;
#pragma unroll
        for (int k4 = 0; k4 < 8; ++k4) {
            float4 av = ar4[k4];
            int kk = kh * 32 + k4 * 4;
            a0 += av.x * WoL[(kk+0)*D+ch];
            a1 += av.y * WoL[(kk+1)*D+ch];
            a2 += av.z * WoL[(kk+2)*D+ch];
            a3 += av.w * WoL[(kk+3)*D+ch];
        }
        ppw[ch] = (a0+a1)+(a2+a3);
    }
    __syncthreads();
    float oo = bo_r + pp[tok4*192 + ch] + pp[(tok4+4)*192 + ch];
    float r = xv + oo;
    float s1 = r, sq1 = r * r;
#pragma unroll
    for (int off = 32; off > 0; off >>= 1) {
        s1 += __shfl_xor(s1, off);
        sq1 += __shfl_xor(sq1, off);
    }
    float mean1 = s1 * (1.0f / D);
    float var1 = sq1 * (1.0f / D) - mean1 * mean1;
    float x1 = l1g * (r - mean1) * rsqrtf(var1 + EPS) + l1b;
    if (kh == 0) xs1[tok4 * D + ch] = x1;
    __syncthreads();

    // ---- FFN1 (split-K, both output halves) ----
    {
        const float4* xr4 = (const float4*)(xs1 + tok4 * D + kh * 32);
        float u0=0.f,u1=0.f,u2=0.f,u3=0.f, g0=0.f,g1=0.f,g2=0.f,g3=0.f;
#pragma unroll
        for (int k4 = 0; k4 < 8; ++k4) {
            float4 xx = xr4[k4];
            int kk = kh * 32 + k4 * 4;
            u0 += xx.x * Wff1L[(kk+0)*128+ch];
            u1 += xx.y * Wff1L[(kk+1)*128+ch];
            u2 += xx.z * Wff1L[(kk+2)*128+ch];
            u3 += xx.w * Wff1L[(kk+3)*128+ch];
            g0 += xx.x * Wff1L[(kk+0)*128+64+ch];
            g1 += xx.y * Wff1L[(kk+1)*128+64+ch];
            g2 += xx.z * Wff1L[(kk+2)*128+64+ch];
            g3 += xx.w * Wff1L[(kk+3)*128+64+ch];
        }
        ppw[ch] = (u0+u1)+(u2+u3);
        ppw[64+ch] = (g0+g1)+(g2+g3);
    }
    __syncthreads();
    // combine: wave handles output half kh
    f1s[tok4*128 + kh*64 + ch] =
        fmaxf(pp[tok4*192 + kh*64 + ch] + pp[(tok4+4)*192 + kh*64 + ch] + bf1_r, 0.f);
    __syncthreads();

    // ---- FFN2 (split-K over 128) ----
    {
        const float4* fr4 = (const float4*)(f1s + tok4*128 + kh*64);
        float e0=0.f,e1=0.f,e2=0.f,e3=0.f;
#pragma unroll
        for (int k4 = 0; k4 < 16; ++k4) {
            float4 fv = fr4[k4];
            int kk = kh*64 + k4*4;
            e0 += fv.x * Wff2L[(kk+0)*D+ch];
            e1 += fv.y * Wff2L[(kk+1)*D+ch];
            e2 += fv.z * Wff2L[(kk+2)*D+ch];
            e3 += fv.w * Wff2L[(kk+3)*D+ch];
        }
        ppw[ch] = (e0+e1)+(e2+e3);
    }
    __syncthreads();
    float o2 = bf2_r + pp[tok4*192 + ch] + pp[(tok4+4)*192 + ch];
    float r2 = x1 + o2;
    float s2 = r2, sq2 = r2 * r2;
#pragma unroll
    for (int off = 32; off > 0; off >>= 1) {
        s2 += __shfl_xor(s2, off);
        sq2 += __shfl_xor(sq2, off);
    }
    float mean2 = s2 * (1.0f / D);
    float var2 = sq2 * (1.0f / D) - mean2 * mean2;
    float xnew = l2g * (r2 - mean2) * rsqrtf(var2 + EPS) + l2b;
    if (kh == 0) x[xidx] = xnew;

    // ---- fused next-layer QKV (block-local) ----
    if (Wqn != nullptr) {
        if (kh == 0) attS[tok4 * D + ch] = xnew;   // attS reads all done (pre-O-proj barrier)
        __syncthreads();
        const float4* xr4 = (const float4*)(attS + tok4 * D + kh * 32);
        float aq0=0.f, aq1=0.f, ak0=0.f, ak1=0.f, av0=0.f, av1=0.f;
#pragma unroll
        for (int k4 = 0; k4 < 8; ++k4) {
            float4 xx = xr4[k4];
            int kk = kh * 32 + k4 * 4;
            aq0 += xx.x * WqnL[(kk+0)*D+ch] + xx.z * WqnL[(kk+2)*D+ch];
            aq1 += xx.y * WqnL[(kk+1)*D+ch] + xx.w * WqnL[(kk+3)*D+ch];
            ak0 += xx.x * WknL[(kk+0)*D+ch] + xx.z * WknL[(kk+2)*D+ch];
            ak1 += xx.y * WknL[(kk+1)*D+ch] + xx.w * WknL[(kk+3)*D+ch];
            av0 += xx.x * WvnL[(kk+0)*D+ch] + xx.z * WvnL[(kk+2)*D+ch];
            av1 += xx.y * WvnL[(kk+1)*D+ch] + xx.w * WvnL[(kk+3)*D+ch];
        }
        ppw[ch] = aq0 + aq1;
        ppw[64+ch] = ak0 + ak1;
        ppw[128+ch] = av0 + av1;
        __syncthreads();
        if (kh == 0) {
            int head = ch >> 4, dh = ch & (DH - 1);
            size_t oidx = (((size_t)(b * NH + head)) * N + token) * DH + dh;
            qo[oidx] = bq_r + pp[tok4*192 + ch] + pp[(tok4+4)*192 + ch];
            ko[oidx] = bk_r + pp[tok4*192 + 64 + ch] + pp[(tok4+4)*192 + 64 + ch];
            vo[oidx] = bv_r + pp[tok4*192 + 128 + ch] + pp[(tok4+4)*192 + 128 + ch];
        }
    }
}

extern "C" void kernel_launch(void* const* d_in, const int* in_sizes, int n_in,
                              void* d_out, int out_size, void* d_ws, size_t ws_size,
                              hipStream_t stream) {
    const float* feature = (const float*)d_in[0];
    const float* W1   = (const float*)d_in[1];
    const float* b1   = (const float*)d_in[2];
    const float* mw   = (const float*)d_in[3];
    const float* mb   = (const float*)d_in[4];
    const float* bn_g = (const float*)d_in[5];
    const float* bn_b = (const float*)d_in[6];
    const float* Wq   = (const float*)d_in[7];
    const float* bq   = (const float*)d_in[8];
    const float* Wk   = (const float*)d_in[9];
    const float* bk   = (const float*)d_in[10];
    const float* Wv   = (const float*)d_in[11];
    const float* bv   = (const float*)d_in[12];
    const float* Wo   = (const float*)d_in[13];
    const float* bo   = (const float*)d_in[14];
    const float* ln1g = (const float*)d_in[15];
    const float* ln1b = (const float*)d_in[16];
    const float* Wff1 = (const float*)d_in[17];
    const float* bff1 = (const float*)d_in[18];
    const float* Wff2 = (const float*)d_in[19];
    const float* bff2 = (const float*)d_in[20];
    const float* ln2g = (const float*)d_in[21];
    const float* ln2b = (const float*)d_in[22];

    float* ws    = (float*)d_ws;
    float* rs    = ws;                     // B*N*NH = 4096
    float* h     = rs + B * N * NH;        // B*N*D  = 65536
    float* bnacc = h + B * N * D;          // 128 (macc|sacc)
    float* q     = bnacc + 128;            // B*N*D
    float* k     = q + B * N * D;          // B*N*D
    float* v     = k + B * N * D;          // B*N*D
    float* x     = (float*)d_out;          // running (B,N,D) activation

    k_rowsum<<<256, 256, 0, stream>>>(feature, W1, b1, mw, mb, rs, bnacc);
    k_aggregate<<<256, 256, 0, stream>>>(feature, W1, b1, mw, mb, rs, h, bnacc);
    k_qkv0<<<256, 512, 0, stream>>>(h, bnacc, bn_g, bn_b,
                                    Wq, bq, Wk, bk, Wv, bv, x, q, k, v);
    // layer 0 (fuses layer-1 QKV), then layer 1
    k_layer<<<dim3(B, N / 4), 512, 0, stream>>>(q, k, v,
        Wo, bo, ln1g, ln1b, Wff1, bff1, Wff2, bff2, ln2g, ln2b,
        Wq + (size_t)D * D, bq + D, Wk + (size_t)D * D, bk + D,
        Wv + (size_t)D * D, bv + D, q, k, v, x);
    k_layer<<<dim3(B, N / 4), 512, 0, stream>>>(q, k, v,
        Wo + (size_t)D * D, bo + D, ln1g + D, ln1b + D,
        Wff1 + (size_t)D * 2 * D, bff1 + 2 * D,
        Wff2 + (size_t)2 * D * D, bff2 + D, ln2g + D, ln2b + D,
        nullptr, nullptr, nullptr, nullptr, nullptr, nullptr,
        nullptr, nullptr, nullptr, x);
}